// Round 17
// baseline (37.769 us; speedup 1.0000x reference)
//
#include <hip/hip_runtime.h>

// Deimv2LQE: out = scores + MLP(top4-softmax-stats(pred_corners))
// 262144 rows; per row 132 f32 (4 corners x 33 bins).
// R17: OCCUPANCY-FIRST. R15's probe (6.3 TB/s) ran at 32 waves/CU with no
//   LDS; R9 (4.3 TB/s) was LDS-capped at ~4 blocks/CU. Fix the LDS/thread
//   ratio: 256-thread block handles only 32 rows; each corner is split
//   across a PAIR of threads (17 bins each, bin16 owned by half0; half1's
//   copy masked to -3e38 -> identical branch-free code). Local top4 +
//   local expsum merged via 5x shfl_xor(lane^1). LDS = 16896+512 B ->
//   8 blocks/CU = 32 waves/CU (100%). Stats embedded at own wave's bin
//   slice head (lockstep WAR-safe). MLP: wave-uniform j-slice, lanes 0-31.
//   __launch_bounds__(256,8) caps VGPR at 64. Grid 8192 short blocks.

#define THREADS 256
#define ROWS 32

typedef float f32x4 __attribute__((ext_vector_type(4), aligned(16)));

__device__ __forceinline__ void sort4d(float& a, float& b, float& c, float& d) {
    float t;
    t = fmaxf(a, b); b = fminf(a, b); a = t;
    t = fmaxf(c, d); d = fminf(c, d); c = t;
    t = fmaxf(a, c); c = fminf(a, c); a = t;
    t = fmaxf(b, d); d = fminf(b, d); b = t;
    t = fmaxf(b, c); c = fminf(b, c); b = t;
}
__device__ __forceinline__ void ins4(float& a, float& b, float& c, float& d,
                                     float x) {
    float t;
    t = fmaxf(a, x); x = fminf(a, x); a = t;
    t = fmaxf(b, x); x = fminf(b, x); b = t;
    t = fmaxf(c, x); x = fminf(c, x); c = t;
    d = fmaxf(d, x);
}
// top-4 of two descending quads -> descending quad in (a0..a3)
__device__ __forceinline__ void merge4(float& a0, float& a1, float& a2,
                                       float& a3, float b0, float b1,
                                       float b2, float b3) {
    a0 = fmaxf(a0, b3);
    a1 = fmaxf(a1, b2);
    a2 = fmaxf(a2, b1);
    a3 = fmaxf(a3, b0);
    sort4d(a0, a1, a2, a3);
}

__global__ __launch_bounds__(THREADS, 8)
void lqe_kernel(const float* __restrict__ scores,
                const float* __restrict__ pc,
                const float* __restrict__ w1,
                const float* __restrict__ b1,
                const float* __restrict__ w2,
                const float* __restrict__ b2,
                float* __restrict__ out)
{
    // 4 wave slices of 1056 floats (8 rows x 132). Stats for wave wv's 8 rows
    // live at its own slice head [wv*1056, wv*1056+168) after corner phase.
    __shared__ f32x4 smStage4[ROWS * 33];    // 16896 B
    __shared__ float smPart[128];            // 512 B
    float* const smStage = (float*)smStage4;

    const int t  = threadIdx.x;
    const int wv = t >> 6;
    const int l  = t & 63;
    const long long rowBase = (long long)blockIdx.x * ROWS;

    float sc = 0.f;
    if (t < ROWS) sc = scores[rowBase + t];

    // ---- stage: 1056 float4, fully contiguous & coalesced ----
    {
        const f32x4* __restrict__ src = (const f32x4*)(pc + rowBase * 132);
        #pragma unroll
        for (int i = 0; i < 4; ++i) smStage4[t + i * 256] = src[t + i * 256];
        if (t < 32) smStage4[1024 + t] = src[1024 + t];
    }
    __syncthreads();

    // ---- split-corner: cid=t>>1 (row=t>>3, corner=(t>>1)&3), half=t&1.
    //      half0 owns bins [0,17); half1 bins [16,33) with bin16 masked. ----
    {
        const int half = t & 1;
        const float* v =
            smStage + (t >> 3) * 132 + ((t >> 1) & 3) * 33 + half * 16;
        float x[17];
        #pragma unroll
        for (int k = 0; k < 17; ++k) x[k] = v[k];
        if (half) x[0] = -3.0e38f;   // avoid double-count of bin16

        float a0 = x[0], a1 = x[1], a2 = x[2], a3 = x[3];
        sort4d(a0, a1, a2, a3);
        #pragma unroll
        for (int k = 4; k < 17; ++k) ins4(a0, a1, a2, a3, x[k]);

        // local exp-sum relative to local max a0 (4 accumulators)
        float sa = 0.f, sb = 0.f, sg = 0.f, sd = 0.f;
        #pragma unroll
        for (int k = 0; k < 16; k += 4) {
            sa += __expf(x[k + 0] - a0);
            sb += __expf(x[k + 1] - a0);
            sg += __expf(x[k + 2] - a0);
            sd += __expf(x[k + 3] - a0);
        }
        sa += __expf(x[16] - a0);
        const float s = (sa + sb) + (sg + sd);

        // exchange with partner lane (t^1): 5 register shuffles, no barrier
        const float o0 = __shfl_xor(a0, 1);
        const float o1 = __shfl_xor(a1, 1);
        const float o2 = __shfl_xor(a2, 1);
        const float o3 = __shfl_xor(a3, 1);
        const float os = __shfl_xor(s, 1);

        float T0 = a0, T1 = a1, T2 = a2, T3 = a3;
        merge4(T0, T1, T2, T3, o0, o1, o2, o3);
        const float S = s * __expf(a0 - T0) + os * __expf(o0 - T0);
        const float inv = 1.0f / S;
        const float p0 = inv;
        const float p1 = __expf(T1 - T0) * inv;
        const float p2 = __expf(T2 - T0) * inv;
        const float p3 = __expf(T3 - T0) * inv;
        const float pm = 0.25f * (p0 + p1 + p2 + p3);

        // even-half writes stats into OWN wave's slice head (WAR-safe:
        // all bin reads above precede these writes in wave program order)
        if (!half) {
            float* sd_ = smStage + wv * 1056 + ((t >> 3) & 7) * 21 +
                         ((t >> 1) & 3) * 5;
            sd_[0] = p0; sd_[1] = p1; sd_[2] = p2; sd_[3] = p3; sd_[4] = pm;
        }
    }
    __syncthreads();

    // ---- MLP: wave wv -> j-slice [16wv,16wv+16); lanes 0-31, row = l ----
    if (l < 32) {
        const int wvs = __builtin_amdgcn_readfirstlane(wv);
        const float* __restrict__ w1s = w1 + wvs * 16;
        const float* __restrict__ w2s = w2 + wvs * 16;
        const float* __restrict__ b1s = b1 + wvs * 16;

        float st[20];
        #pragma unroll
        for (int k = 0; k < 20; ++k)
            st[k] = smStage[(l >> 3) * 1056 + (l & 7) * 21 + k];

        float h[16];
        #pragma unroll
        for (int j = 0; j < 16; ++j) h[j] = b1s[j];
        #pragma unroll
        for (int k = 0; k < 20; ++k) {
            #pragma unroll
            for (int j = 0; j < 16; ++j)
                h[j] = fmaf(st[k], w1s[k * 64 + j], h[j]);
        }
        float acc0 = 0.f, acc1 = 0.f, acc2 = 0.f, acc3 = 0.f;
        #pragma unroll
        for (int j = 0; j < 16; j += 4) {
            acc0 = fmaf(fmaxf(h[j + 0], 0.f), w2s[j + 0], acc0);
            acc1 = fmaf(fmaxf(h[j + 1], 0.f), w2s[j + 1], acc1);
            acc2 = fmaf(fmaxf(h[j + 2], 0.f), w2s[j + 2], acc2);
            acc3 = fmaf(fmaxf(h[j + 3], 0.f), w2s[j + 3], acc3);
        }
        smPart[wvs * 32 + l] = (acc0 + acc1) + (acc2 + acc3);
    }
    __syncthreads();

    // ---- reduce 4 j-slice partials, add score, coalesced store ----
    if (t < ROWS) {
        const float r = (smPart[t] + smPart[32 + t]) +
                        (smPart[64 + t] + smPart[96 + t]);
        out[rowBase + t] = sc + r + b2[0];
    }
}

extern "C" void kernel_launch(void* const* d_in, const int* in_sizes, int n_in,
                              void* d_out, int out_size, void* d_ws, size_t ws_size,
                              hipStream_t stream) {
    const float* scores = (const float*)d_in[0];
    const float* pc     = (const float*)d_in[1];
    const float* w1     = (const float*)d_in[2];
    const float* b1     = (const float*)d_in[3];
    const float* w2     = (const float*)d_in[4];
    const float* b2     = (const float*)d_in[5];
    float* out = (float*)d_out;

    const int rows = out_size;          // 262144
    const int blocks = rows / ROWS;     // 8192
    lqe_kernel<<<blocks, THREADS, 0, stream>>>(scores, pc, w1, b1, w2, b2, out);
}